// Round 1
// baseline (85.341 us; speedup 1.0000x reference)
//
#include <hip/hip_runtime.h>

#define NB    32      // batch
#define CIN   512     // IN_CH
#define MID2  1024    // MAX_MID*2
#define MID   512     // MAX_MID
#define HW    4096    // 64*64

// ---------------- Kernel 1: global average pool ----------------
// One block per (b,c) row: reduce 4096 contiguous floats.
__global__ __launch_bounds__(256) void k_gap(const float* __restrict__ x,
                                             float* __restrict__ gap) {
    const int row = blockIdx.x;                       // b*CIN + c
    const float4* x4 = (const float4*)(x + (size_t)row * HW);
    const int t = threadIdx.x;
    float s = 0.f;
#pragma unroll
    for (int it = 0; it < 4; ++it) {
        float4 v = x4[it * 256 + t];
        s += (v.x + v.y) + (v.z + v.w);
    }
    for (int off = 32; off; off >>= 1) s += __shfl_down(s, off, 64);
    __shared__ float wsum[4];
    const int wid = t >> 6, lane = t & 63;
    if (lane == 0) wsum[wid] = s;
    __syncthreads();
    if (t == 0) {
        gap[row] = (wsum[0] + wsum[1] + wsum[2] + wsum[3]) * (1.0f / HW);
    }
}

// ---------------- Kernel 2: fc1 + ReLU ----------------
// One wave (64 lanes) per output element h[b][j], K = 512.
__global__ __launch_bounds__(256) void k_fc1(const float* __restrict__ gap,
                                             const float* __restrict__ w1,
                                             const float* __restrict__ b1,
                                             float* __restrict__ h) {
    const int wid = threadIdx.x >> 6, lane = threadIdx.x & 63;
    const int o = blockIdx.x * 4 + wid;               // 0 .. NB*MID2-1
    const int b = o >> 10;                            // o / MID2
    const int j = o & (MID2 - 1);
    const float* g = gap + b * CIN;
    const float* w = w1 + (size_t)j * CIN;
    float s = 0.f;
#pragma unroll
    for (int i = 0; i < CIN / 64; ++i) {
        const int idx = i * 64 + lane;
        s += g[idx] * w[idx];
    }
    for (int off = 32; off; off >>= 1) s += __shfl_down(s, off, 64);
    if (lane == 0) h[o] = fmaxf(s + b1[j], 0.f);
}

// ---------------- Kernel 3: fc2 + sigmoid ----------------
// One wave per output element scores[b][m], K = 1024.
__global__ __launch_bounds__(256) void k_fc2(const float* __restrict__ h,
                                             const float* __restrict__ w2,
                                             const float* __restrict__ b2,
                                             float* __restrict__ scores) {
    const int wid = threadIdx.x >> 6, lane = threadIdx.x & 63;
    const int o = blockIdx.x * 4 + wid;               // 0 .. NB*MID-1
    const int b = o >> 9;                             // o / MID
    const int m = o & (MID - 1);
    const float* hh = h + b * MID2;
    const float* w = w2 + (size_t)m * MID2;
    float s = 0.f;
#pragma unroll
    for (int i = 0; i < MID2 / 64; ++i) {
        const int idx = i * 64 + lane;
        s += hh[idx] * w[idx];
    }
    for (int off = 32; off; off >>= 1) s += __shfl_down(s, off, 64);
    if (lane == 0) {
        const float v = s + b2[m];
        scores[o] = 1.0f / (1.0f + __expf(-v));
    }
}

// ---------------- Kernel 4: mean -> scale -> k ----------------
__global__ __launch_bounds__(256) void k_scale(const float* __restrict__ scores,
                                               float* __restrict__ out_k,
                                               int* __restrict__ ws_k) {
    float s = 0.f;
    for (int i = threadIdx.x; i < NB * MID; i += 256) s += scores[i];
    for (int off = 32; off; off >>= 1) s += __shfl_down(s, off, 64);
    __shared__ float wsum[4];
    const int wid = threadIdx.x >> 6, lane = threadIdx.x & 63;
    if (lane == 0) wsum[wid] = s;
    __syncthreads();
    if (threadIdx.x == 0) {
        const float mean = (wsum[0] + wsum[1] + wsum[2] + wsum[3]) / (float)(NB * MID);
        const float scale = fminf(fmaxf(mean, 0.25f), 1.0f);
        int k = (int)ceilf((float)MID * scale);
        k = min(max(k, 128), MID);                    // k_min = max(4, 512/4) = 128
        out_k[0] = (float)k;
        ws_k[0] = k;
    }
}

// ---------------- Kernel 5: per-row k-th largest + mask ----------------
// 32 blocks x 512 threads. Rank-count selection: the k-th largest value v
// satisfies count(>v) < k <= count(>=v). Tie-safe, matches sort+take.
__global__ __launch_bounds__(512) void k_mask(const float* __restrict__ scores,
                                              const int* __restrict__ ws_k,
                                              float* __restrict__ mask) {
    __shared__ float srow[MID];
    __shared__ float thr;
    const int b = blockIdx.x, t = threadIdx.x;
    const float v = scores[b * MID + t];
    srow[t] = v;
    __syncthreads();
    const int k = ws_k[0];
    int gt = 0, ge = 0;
    for (int i = 0; i < MID; ++i) {
        const float u = srow[i];   // uniform address -> LDS broadcast, no conflict
        gt += (u > v);
        ge += (u >= v);
    }
    if (gt < k && ge >= k) thr = v;   // all satisfying threads hold the same value
    __syncthreads();
    mask[b * MID + t] = (v >= thr) ? 1.0f : 0.0f;
}

extern "C" void kernel_launch(void* const* d_in, const int* in_sizes, int n_in,
                              void* d_out, int out_size, void* d_ws, size_t ws_size,
                              hipStream_t stream) {
    const float* x  = (const float*)d_in[0];
    const float* w1 = (const float*)d_in[1];
    const float* b1 = (const float*)d_in[2];
    const float* w2 = (const float*)d_in[3];
    const float* b2 = (const float*)d_in[4];
    float* out = (float*)d_out;

    float* gap    = (float*)d_ws;            // NB*CIN   = 16384 floats
    float* h      = gap + NB * CIN;          // NB*MID2  = 32768 floats
    float* scores = h + NB * MID2;           // NB*MID   = 16384 floats
    int*   kptr   = (int*)(scores + NB * MID);

    k_gap  <<<NB * CIN,        256, 0, stream>>>(x, gap);
    k_fc1  <<<NB * MID2 / 4,   256, 0, stream>>>(gap, w1, b1, h);
    k_fc2  <<<NB * MID  / 4,   256, 0, stream>>>(h, w2, b2, scores);
    k_scale<<<1,               256, 0, stream>>>(scores, out + NB * MID, kptr);
    k_mask <<<NB,              512, 0, stream>>>(scores, kptr, out);
}

// Round 2
// 68.820 us; speedup vs baseline: 1.2401x; 1.2401x over previous
//
#include <hip/hip_runtime.h>

#define NB    32      // batch
#define CIN   512     // IN_CH
#define MID2  1024    // MAX_MID*2
#define MID   512     // MAX_MID
#define HW    4096    // 64*64

// ---------------- Kernel 1: global average pool ----------------
// One wave per (b,c) row: 16 float4 loads per lane (1 KiB/instr/wave,
// fully unrolled -> 16 loads in flight), shuffle-only reduce, no LDS.
__global__ __launch_bounds__(64) void k_gap(const float* __restrict__ x,
                                            float* __restrict__ gap) {
    const int row = blockIdx.x;                       // b*CIN + c
    const float4* x4 = (const float4*)(x + (size_t)row * HW);
    const int lane = threadIdx.x;
    float s0 = 0.f, s1 = 0.f, s2 = 0.f, s3 = 0.f;
#pragma unroll
    for (int it = 0; it < 4; ++it) {
        float4 a = x4[(4 * it + 0) * 64 + lane];
        float4 b = x4[(4 * it + 1) * 64 + lane];
        float4 c = x4[(4 * it + 2) * 64 + lane];
        float4 d = x4[(4 * it + 3) * 64 + lane];
        s0 += (a.x + a.y) + (a.z + a.w);
        s1 += (b.x + b.y) + (b.z + b.w);
        s2 += (c.x + c.y) + (c.z + c.w);
        s3 += (d.x + d.y) + (d.z + d.w);
    }
    float s = (s0 + s1) + (s2 + s3);
    for (int off = 32; off; off >>= 1) s += __shfl_down(s, off, 64);
    if (lane == 0) gap[row] = s * (1.0f / HW);
}

// ---------------- Kernel 2: fc1 + ReLU ----------------
// One wave per output element h[b][j], K = 512, coalesced w1 row reads.
__global__ __launch_bounds__(256) void k_fc1(const float* __restrict__ gap,
                                             const float* __restrict__ w1,
                                             const float* __restrict__ b1,
                                             float* __restrict__ h) {
    const int wid = threadIdx.x >> 6, lane = threadIdx.x & 63;
    const int o = blockIdx.x * 4 + wid;               // 0 .. NB*MID2-1
    const int b = o >> 10;                            // o / MID2
    const int j = o & (MID2 - 1);
    const float* g = gap + b * CIN;
    const float* w = w1 + (size_t)j * CIN;
    float s = 0.f;
#pragma unroll
    for (int i = 0; i < CIN / 64; ++i) {
        const int idx = i * 64 + lane;
        s += g[idx] * w[idx];
    }
    for (int off = 32; off; off >>= 1) s += __shfl_down(s, off, 64);
    if (lane == 0) h[o] = fmaxf(s + b1[j], 0.f);
}

// ---------------- Kernel 3: fc2 + sigmoid ----------------
// One wave per output element scores[b][m], K = 1024.
__global__ __launch_bounds__(256) void k_fc2(const float* __restrict__ h,
                                             const float* __restrict__ w2,
                                             const float* __restrict__ b2,
                                             float* __restrict__ scores) {
    const int wid = threadIdx.x >> 6, lane = threadIdx.x & 63;
    const int o = blockIdx.x * 4 + wid;               // 0 .. NB*MID-1
    const int b = o >> 9;                             // o / MID
    const int m = o & (MID - 1);
    const float* hh = h + b * MID2;
    const float* w = w2 + (size_t)m * MID2;
    float s = 0.f;
#pragma unroll
    for (int i = 0; i < MID2 / 64; ++i) {
        const int idx = i * 64 + lane;
        s += hh[idx] * w[idx];
    }
    for (int off = 32; off; off >>= 1) s += __shfl_down(s, off, 64);
    if (lane == 0) {
        const float v = s + b2[m];
        scores[o] = 1.0f / (1.0f + __expf(-v));
    }
}

// ---------------- Kernel 4: fused mean->k->threshold->mask ----------------
// 32 blocks x 512 threads. Every block redundantly computes the global mean
// (identical FP order -> identical k in all blocks, deterministic), then
// rank-count selection for its own row. Tie-safe: the k-th largest value v
// satisfies count(>v) < k <= count(>=v).
__global__ __launch_bounds__(512) void k_mask(const float* __restrict__ scores,
                                              float* __restrict__ out) {
    __shared__ float srow[MID];
    __shared__ float red[8];
    __shared__ float thr;
    const int b = blockIdx.x, t = threadIdx.x;

    // global mean over all NB*MID scores (L2-resident, 64 KiB)
    float s = 0.f;
#pragma unroll
    for (int i = 0; i < NB * MID / 512; ++i) s += scores[i * 512 + t];
    for (int off = 32; off; off >>= 1) s += __shfl_down(s, off, 64);
    const int wid = t >> 6, lane = t & 63;
    if (lane == 0) red[wid] = s;

    const float v = scores[b * MID + t];
    srow[t] = v;
    __syncthreads();

    const float tot = ((red[0] + red[1]) + (red[2] + red[3])) +
                      ((red[4] + red[5]) + (red[6] + red[7]));
    const float mean = tot / (float)(NB * MID);
    const float scale = fminf(fmaxf(mean, 0.25f), 1.0f);
    int k = (int)ceilf((float)MID * scale);
    k = min(max(k, 128), MID);                        // k_min = max(4, 512/4) = 128

    // rank-count vs own value, float4 LDS reads (uniform addr -> broadcast)
    const float4* srow4 = (const float4*)srow;
    int gt = 0, ge = 0;
    for (int i = 0; i < MID / 4; ++i) {
        const float4 u = srow4[i];
        gt += (u.x > v) + (u.y > v) + (u.z > v) + (u.w > v);
        ge += (u.x >= v) + (u.y >= v) + (u.z >= v) + (u.w >= v);
    }
    if (gt < k && ge >= k) thr = v;   // all satisfying threads hold the same value
    __syncthreads();
    out[b * MID + t] = (v >= thr) ? 1.0f : 0.0f;
    if (b == 0 && t == 0) out[NB * MID] = (float)k;
}

extern "C" void kernel_launch(void* const* d_in, const int* in_sizes, int n_in,
                              void* d_out, int out_size, void* d_ws, size_t ws_size,
                              hipStream_t stream) {
    const float* x  = (const float*)d_in[0];
    const float* w1 = (const float*)d_in[1];
    const float* b1 = (const float*)d_in[2];
    const float* w2 = (const float*)d_in[3];
    const float* b2 = (const float*)d_in[4];
    float* out = (float*)d_out;

    float* gap    = (float*)d_ws;            // NB*CIN   = 16384 floats
    float* h      = gap + NB * CIN;          // NB*MID2  = 32768 floats
    float* scores = h + NB * MID2;           // NB*MID   = 16384 floats

    k_gap <<<NB * CIN,      64,  0, stream>>>(x, gap);
    k_fc1 <<<NB * MID2 / 4, 256, 0, stream>>>(gap, w1, b1, h);
    k_fc2 <<<NB * MID  / 4, 256, 0, stream>>>(h, w2, b2, scores);
    k_mask<<<NB,            512, 0, stream>>>(scores, out);
}